// Round 1
// baseline (166.556 us; speedup 1.0000x reference)
//
#include <hip/hip_runtime.h>
#include <hip/hip_bf16.h>
#include <math.h>

// Phase 1: A = x @ W1[0:128, :], B = x @ W1[128:256, :]   (both [nNodes][128], fp32)
// One block = 32 nodes, 128 threads (thread j owns hidden column j).
__global__ __launch_bounds__(128) void ep_precompute(
    const float* __restrict__ x, const float* __restrict__ W1,
    float* __restrict__ A, float* __restrict__ B, int nNodes)
{
    __shared__ float xs[32][128];   // 16 KiB
    const int j = threadIdx.x;      // 0..127 hidden column
    const int node0 = blockIdx.x * 32;
    const int valid = min(32, nNodes - node0);

    // cooperative x-tile load: 32 rows x 32 float4
    {
        const float4* xsrc = reinterpret_cast<const float4*>(x) + (size_t)node0 * 32;
        float4* xdst = reinterpret_cast<float4*>(&xs[0][0]);
        for (int t = j; t < 32 * 32; t += 128) {
            const int r = t >> 5;
            xdst[t] = (r < valid) ? xsrc[t] : make_float4(0.f, 0.f, 0.f, 0.f);
        }
    }
    __syncthreads();

    float accA[32], accB[32];
    #pragma unroll
    for (int m = 0; m < 32; ++m) { accA[m] = 0.f; accB[m] = 0.f; }

    for (int k = 0; k < 128; k += 4) {
        // W1 is [256][128] row-major; column j, rows k..k+3 (top half) and k+128.. (bottom)
        const float wa0 = W1[(k + 0) * 128 + j];
        const float wa1 = W1[(k + 1) * 128 + j];
        const float wa2 = W1[(k + 2) * 128 + j];
        const float wa3 = W1[(k + 3) * 128 + j];
        const float wb0 = W1[(k + 128) * 128 + j];
        const float wb1 = W1[(k + 129) * 128 + j];
        const float wb2 = W1[(k + 130) * 128 + j];
        const float wb3 = W1[(k + 131) * 128 + j];
        #pragma unroll
        for (int m = 0; m < 32; ++m) {
            const float4 xv = *reinterpret_cast<const float4*>(&xs[m][k]);  // LDS broadcast
            accA[m] = fmaf(xv.x, wa0, accA[m]);
            accA[m] = fmaf(xv.y, wa1, accA[m]);
            accA[m] = fmaf(xv.z, wa2, accA[m]);
            accA[m] = fmaf(xv.w, wa3, accA[m]);
            accB[m] = fmaf(xv.x, wb0, accB[m]);
            accB[m] = fmaf(xv.y, wb1, accB[m]);
            accB[m] = fmaf(xv.z, wb2, accB[m]);
            accB[m] = fmaf(xv.w, wb3, accB[m]);
        }
    }

    #pragma unroll
    for (int m = 0; m < 32; ++m) {
        const int node = node0 + m;
        if (node < nNodes) {
            A[(size_t)node * 128 + j] = accA[m];
            B[(size_t)node * 128 + j] = accB[m];
        }
    }
}

// Phase 2: out[e] = sigmoid( relu(A[row] + B[col] + b1) . W2 + b2 )
// 16 consecutive lanes own one edge; lane `sub` owns elems [sub*4, sub*4+4) and [64+sub*4, ..).
__global__ __launch_bounds__(256) void ep_edges(
    const int* __restrict__ ei, const float* __restrict__ A, const float* __restrict__ B,
    const float* __restrict__ b1, const float* __restrict__ W2, const float* __restrict__ b2,
    float* __restrict__ out, int E)
{
    const int sub = threadIdx.x & 15;
    const float4* b14 = reinterpret_cast<const float4*>(b1);
    const float4* w24 = reinterpret_cast<const float4*>(W2);
    const float4 bl = b14[sub], bh = b14[16 + sub];
    const float4 wl = w24[sub], wh = w24[16 + sub];
    const float b2v = b2[0];
    const float4* A4 = reinterpret_cast<const float4*>(A);
    const float4* B4 = reinterpret_cast<const float4*>(B);

    const size_t stride = ((size_t)gridDim.x * blockDim.x) >> 4;
    for (size_t e = ((size_t)blockIdx.x * blockDim.x + threadIdx.x) >> 4;
         e < (size_t)E; e += stride) {
        const size_t r = (size_t)(unsigned)ei[e];
        const size_t c = (size_t)(unsigned)ei[E + e];

        const float4 alo = A4[r * 32 + sub];        // bytes [sub*16 .. ) of 256B seg 0
        const float4 ahi = A4[r * 32 + 16 + sub];   // seg 1
        const float4 vlo = B4[c * 32 + sub];
        const float4 vhi = B4[c * 32 + 16 + sub];

        float p = 0.f, h;
        h = fmaxf(alo.x + vlo.x + bl.x, 0.f); p = fmaf(h, wl.x, p);
        h = fmaxf(alo.y + vlo.y + bl.y, 0.f); p = fmaf(h, wl.y, p);
        h = fmaxf(alo.z + vlo.z + bl.z, 0.f); p = fmaf(h, wl.z, p);
        h = fmaxf(alo.w + vlo.w + bl.w, 0.f); p = fmaf(h, wl.w, p);
        h = fmaxf(ahi.x + vhi.x + bh.x, 0.f); p = fmaf(h, wh.x, p);
        h = fmaxf(ahi.y + vhi.y + bh.y, 0.f); p = fmaf(h, wh.y, p);
        h = fmaxf(ahi.z + vhi.z + bh.z, 0.f); p = fmaf(h, wh.z, p);
        h = fmaxf(ahi.w + vhi.w + bh.w, 0.f); p = fmaf(h, wh.w, p);

        // reduce across the 16-lane group (stays inside the 64-lane wave)
        p += __shfl_xor(p, 1);
        p += __shfl_xor(p, 2);
        p += __shfl_xor(p, 4);
        p += __shfl_xor(p, 8);

        if (sub == 0) out[e] = 1.f / (1.f + expf(-(p + b2v)));
    }
}

extern "C" void kernel_launch(void* const* d_in, const int* in_sizes, int n_in,
                              void* d_out, int out_size, void* d_ws, size_t ws_size,
                              hipStream_t stream) {
    const float* x  = (const float*)d_in[0];
    const int*   ei = (const int*)  d_in[1];   // harness delivers integer inputs as int32
    const float* W1 = (const float*)d_in[2];
    const float* b1 = (const float*)d_in[3];
    const float* W2 = (const float*)d_in[4];
    const float* b2 = (const float*)d_in[5];
    float* out = (float*)d_out;

    const int nNodes = in_sizes[0] / 128;     // 50000
    const int E      = in_sizes[1] / 2;       // 600000

    float* A = (float*)d_ws;                              // nNodes*128 floats
    float* B = A + (size_t)nNodes * 128;                  // nNodes*128 floats (51.2 MB total)

    const int pre_blocks = (nNodes + 31) / 32;
    ep_precompute<<<pre_blocks, 128, 0, stream>>>(x, W1, A, B, nNodes);

    const int needed = (E * 16 + 255) / 256;              // one 16-lane group per edge
    const int edge_blocks = needed < 4096 ? needed : 4096;
    ep_edges<<<edge_blocks, 256, 0, stream>>>(ei, A, B, b1, W2, b2, out, E);
}

// Round 2
// 88.465 us; speedup vs baseline: 1.8827x; 1.8827x over previous
//
#include <hip/hip_runtime.h>
#include <hip/hip_bf16.h>
#include <math.h>

typedef __attribute__((ext_vector_type(8))) short short8;
typedef __attribute__((ext_vector_type(4))) float f32x4;

static __device__ __forceinline__ unsigned short f2bf(float f) {
    __hip_bfloat16 h = __float2bfloat16(f);
    return *reinterpret_cast<unsigned short*>(&h);
}
static __device__ __forceinline__ float bf2f(unsigned short u) {
    unsigned int x = ((unsigned int)u) << 16;
    return *reinterpret_cast<float*>(&x);
}

// Phase 1: [A | B] = x @ [W1top | W1bot]  via bf16 MFMA, outputs stored bf16.
// Grid: Mblk = bid>>2 (128 nodes each), Nblk = bid&3 (64 output cols each;
// Nblk 0,1 -> A cols 0-63,64-127; Nblk 2,3 -> B cols 0-63,64-127).
// Block: 256 threads = 4 waves (2x2), per-wave 64x32 output, K=128 in one LDS stage.
// LDS layout [kb][row][8 bf16] so an A/B fragment is ONE ds_read_b128:
// lane l of mfma_16x16x32 holds row/col = l&15, k = (l>>4)*8 + 0..7.
#define BM 128
#define BN 64

__global__ __launch_bounds__(256) void ep_gemm(
    const float* __restrict__ x, const float* __restrict__ W1,
    unsigned short* __restrict__ A, unsigned short* __restrict__ B, int nNodes)
{
    __shared__ short8 xs[16 * BM];   // 32 KiB: [kb][row]
    __shared__ short8 ws[16 * BN];   // 16 KiB: [kb][ncol]

    const int tid   = threadIdx.x;
    const int Mblk  = blockIdx.x >> 2;
    const int Nblk  = blockIdx.x & 3;
    const int node0 = Mblk * BM;
    const int koff  = (Nblk >= 2) ? 128 : 0;      // which W1 half (rows)
    const int ncol0 = (Nblk & 1) * 64;            // col offset within the half
    unsigned short* __restrict__ outp = (Nblk >= 2) ? B : A;

    // stage x tile: 2048 chunks of 8 elems (row, kb), fp32 -> bf16
    #pragma unroll
    for (int i = 0; i < 8; ++i) {
        const int c = tid + i * 256;
        const int row = c >> 4, kb = c & 15;
        const int node = node0 + row;
        short8 v;
        if (node < nNodes) {
            const float4* src = reinterpret_cast<const float4*>(x + (size_t)node * 128 + kb * 8);
            const float4 p0 = src[0], p1 = src[1];
            v[0] = (short)f2bf(p0.x); v[1] = (short)f2bf(p0.y);
            v[2] = (short)f2bf(p0.z); v[3] = (short)f2bf(p0.w);
            v[4] = (short)f2bf(p1.x); v[5] = (short)f2bf(p1.y);
            v[6] = (short)f2bf(p1.z); v[7] = (short)f2bf(p1.w);
        } else {
            v = short8{0, 0, 0, 0, 0, 0, 0, 0};
        }
        xs[kb * BM + row] = v;
    }
    // stage W tile (transposed: [kb][ncol][8k]): 1024 chunks, 8 strided scalar
    // loads each (W1 is 128 KiB, L2-resident, reused by all M-blocks)
    #pragma unroll
    for (int i = 0; i < 4; ++i) {
        const int c = tid + i * 256;
        const int nl = c >> 4, kb = c & 15;
        const int col = ncol0 + nl;
        short8 v;
        #pragma unroll
        for (int j = 0; j < 8; ++j)
            v[j] = (short)f2bf(W1[(size_t)(koff + kb * 8 + j) * 128 + col]);
        ws[kb * BN + nl] = v;
    }
    __syncthreads();

    const int w = tid >> 6, lane = tid & 63;
    const int wm = (w >> 1) * 64, wn = (w & 1) * 32;
    const int lrow = lane & 15, lkb = lane >> 4;

    f32x4 acc[4][2];
    #pragma unroll
    for (int mt = 0; mt < 4; ++mt)
        #pragma unroll
        for (int nt = 0; nt < 2; ++nt)
            acc[mt][nt] = f32x4{0.f, 0.f, 0.f, 0.f};

    #pragma unroll
    for (int s = 0; s < 4; ++s) {
        short8 af[4], bfr[2];
        #pragma unroll
        for (int mt = 0; mt < 4; ++mt)
            af[mt] = xs[(s * 4 + lkb) * BM + wm + mt * 16 + lrow];
        #pragma unroll
        for (int nt = 0; nt < 2; ++nt)
            bfr[nt] = ws[(s * 4 + lkb) * BN + wn + nt * 16 + lrow];
        #pragma unroll
        for (int mt = 0; mt < 4; ++mt)
            #pragma unroll
            for (int nt = 0; nt < 2; ++nt)
                acc[mt][nt] = __builtin_amdgcn_mfma_f32_16x16x32_bf16(
                    af[mt], bfr[nt], acc[mt][nt], 0, 0, 0);
    }

    // C/D layout (m89-verified): col = lane&15, row = (lane>>4)*4 + reg
    const int crow0 = (lane >> 4) * 4;
    #pragma unroll
    for (int mt = 0; mt < 4; ++mt) {
        #pragma unroll
        for (int r = 0; r < 4; ++r) {
            const int m = node0 + wm + mt * 16 + crow0 + r;
            if (m < nNodes) {
                #pragma unroll
                for (int nt = 0; nt < 2; ++nt)
                    outp[(size_t)m * 128 + ncol0 + wn + nt * 16 + lrow] =
                        f2bf(acc[mt][nt][r]);
            }
        }
    }
}

// Phase 2: out[e] = sigmoid( relu(A[row] + B[col] + b1) . W2 + b2 )
// 16 lanes per edge; lane sub owns hidden elems [sub*8, sub*8+8).
// A/B rows are bf16: 256 B each = 16 lanes x one b128 load. 
__global__ __launch_bounds__(256) void ep_edges(
    const int* __restrict__ ei,
    const unsigned short* __restrict__ A, const unsigned short* __restrict__ B,
    const float* __restrict__ b1, const float* __restrict__ W2,
    const float* __restrict__ b2, float* __restrict__ out, int E)
{
    const int sub = threadIdx.x & 15;
    float b1f[8], w2f[8];
    #pragma unroll
    for (int j = 0; j < 8; ++j) {
        b1f[j] = b1[sub * 8 + j];
        w2f[j] = W2[sub * 8 + j];
    }
    const float b2v = b2[0];

    const size_t stride = ((size_t)gridDim.x * blockDim.x) >> 4;
    for (size_t e = ((size_t)blockIdx.x * blockDim.x + threadIdx.x) >> 4;
         e < (size_t)E; e += stride) {
        const size_t r = (size_t)(unsigned)ei[e];
        const size_t c = (size_t)(unsigned)ei[E + e];

        const short8 a8 = *reinterpret_cast<const short8*>(A + r * 128 + sub * 8);
        const short8 v8 = *reinterpret_cast<const short8*>(B + c * 128 + sub * 8);

        float p = 0.f;
        #pragma unroll
        for (int j = 0; j < 8; ++j) {
            const float h = fmaxf(bf2f((unsigned short)a8[j]) +
                                  bf2f((unsigned short)v8[j]) + b1f[j], 0.f);
            p = fmaf(h, w2f[j], p);
        }

        p += __shfl_xor(p, 1);
        p += __shfl_xor(p, 2);
        p += __shfl_xor(p, 4);
        p += __shfl_xor(p, 8);

        if (sub == 0) out[e] = 1.f / (1.f + expf(-(p + b2v)));
    }
}

extern "C" void kernel_launch(void* const* d_in, const int* in_sizes, int n_in,
                              void* d_out, int out_size, void* d_ws, size_t ws_size,
                              hipStream_t stream) {
    const float* x  = (const float*)d_in[0];
    const int*   ei = (const int*)  d_in[1];
    const float* W1 = (const float*)d_in[2];
    const float* b1 = (const float*)d_in[3];
    const float* W2 = (const float*)d_in[4];
    const float* b2 = (const float*)d_in[5];
    float* out = (float*)d_out;

    const int nNodes = in_sizes[0] / 128;     // 50000
    const int E      = in_sizes[1] / 2;       // 600000

    unsigned short* A = (unsigned short*)d_ws;            // [nNodes][128] bf16
    unsigned short* B = A + (size_t)nNodes * 128;         // [nNodes][128] bf16 (25.6 MB total)

    const int mblocks = (nNodes + BM - 1) / BM;
    ep_gemm<<<mblocks * 4, 256, 0, stream>>>(x, W1, A, B, nNodes);

    const int needed = (int)(((size_t)E * 16 + 255) / 256);
    const int edge_blocks = needed < 4096 ? needed : 4096;
    ep_edges<<<edge_blocks, 256, 0, stream>>>(ei, A, B, b1, W2, b2, out, E);
}

// Round 3
// 68.274 us; speedup vs baseline: 2.4395x; 1.2957x over previous
//
#include <hip/hip_runtime.h>
#include <hip/hip_bf16.h>
#include <math.h>

typedef __attribute__((ext_vector_type(8))) short short8;
typedef __attribute__((ext_vector_type(4))) float f32x4;

static __device__ __forceinline__ unsigned short f2bf(float f) {
    __hip_bfloat16 h = __float2bfloat16(f);
    return *reinterpret_cast<unsigned short*>(&h);
}
static __device__ __forceinline__ float bf2f(unsigned short u) {
    unsigned int x = ((unsigned int)u) << 16;
    return *reinterpret_cast<float*>(&x);
}

// Prep: W1s[h][kb][col][j] = bf16(W1[h*128 + kb*8 + j][col])
// h in {0,1} (top/bottom half of W1), kb 0..15, col 0..127, j 0..7.
// Exactly the ws LDS layout ep_gemm wants, so gemm staging is a linear copy.
// Reads coalesced (consecutive threads -> consecutive col), writes coalesced.
__global__ __launch_bounds__(256) void ep_prepw(
    const float* __restrict__ W1, unsigned short* __restrict__ W1s)
{
    const int gid = blockIdx.x * 256 + threadIdx.x;   // 4096 = 2*16*128
    const int h   = gid >> 11;
    const int kb  = (gid >> 7) & 15;
    const int col = gid & 127;
    short8 v;
    #pragma unroll
    for (int j = 0; j < 8; ++j)
        v[j] = (short)f2bf(W1[(size_t)(h * 128 + kb * 8 + j) * 128 + col]);
    reinterpret_cast<short8*>(W1s)[gid] = v;
}

// Phase 1: [A | B] = x @ [W1top | W1bot]  via bf16 MFMA, outputs stored bf16.
// 4 sibling blocks per Mblk (Nblk 0..3); bijective XCD swizzle keeps siblings
// on one XCD so the x-tile is fetched from HBM once per Mblk.
// xs slot = kb*128 + (row^kb): staging writes hit the 8-access/bank floor
// (unswizzled: 16 lanes x 2048B stride = same bank = ~64 cyc/instr).
#define BM 128
#define BN 64

__global__ __launch_bounds__(256) void ep_gemm(
    const float* __restrict__ x, const unsigned short* __restrict__ W1s,
    unsigned short* __restrict__ A, unsigned short* __restrict__ B,
    int nNodes, int nwg)
{
    __shared__ short8 xs[16 * BM];   // 32 KiB: [kb][row^kb]
    __shared__ short8 ws[16 * BN];   // 16 KiB: [kb][ncol]

    const int tid = threadIdx.x;

    // bijective XCD grouping (m204): consecutive gi land on the same XCD
    const int orig = blockIdx.x;
    const int q = nwg >> 3, r = nwg & 7;
    const int xcd = orig & 7, within = orig >> 3;
    const int base = (xcd < r) ? xcd * (q + 1) : r * (q + 1) + (xcd - r) * q;
    const int gi = base + within;

    const int Mblk  = gi >> 2;
    const int Nblk  = gi & 3;
    const int node0 = Mblk * BM;
    const int h     = (Nblk >= 2) ? 1 : 0;        // which W1 half
    const int ncol0 = (Nblk & 1) * 64;            // col offset within the half
    unsigned short* __restrict__ outp = h ? B : A;

    // stage x tile: 2048 chunks (row, kb); global reads coalesced (16 lanes
    // cover one row's 512 B); LDS slot swizzled conflict-free
    #pragma unroll
    for (int i = 0; i < 8; ++i) {
        const int c = tid + i * 256;
        const int row = c >> 4, kb = c & 15;
        const int node = node0 + row;
        short8 v;
        if (node < nNodes) {
            const float4* src = reinterpret_cast<const float4*>(x + (size_t)node * 128 + kb * 8);
            const float4 p0 = src[0], p1 = src[1];
            v[0] = (short)f2bf(p0.x); v[1] = (short)f2bf(p0.y);
            v[2] = (short)f2bf(p0.z); v[3] = (short)f2bf(p0.w);
            v[4] = (short)f2bf(p1.x); v[5] = (short)f2bf(p1.y);
            v[6] = (short)f2bf(p1.z); v[7] = (short)f2bf(p1.w);
        } else {
            v = short8{0, 0, 0, 0, 0, 0, 0, 0};
        }
        xs[kb * BM + (row ^ kb)] = v;
    }
    // stage W tile: linear b128 copy from pre-transposed W1s (L2-resident)
    #pragma unroll
    for (int i = 0; i < 4; ++i) {
        const int c = tid + i * 256;               // c = kb*64 + nl
        const int kb = c >> 6, nl = c & 63;
        ws[c] = reinterpret_cast<const short8*>(W1s)[(h * 16 + kb) * 128 + ncol0 + nl];
    }
    __syncthreads();

    const int w = tid >> 6, lane = tid & 63;
    const int wm = (w >> 1) * 64, wn = (w & 1) * 32;
    const int lrow = lane & 15, lkb = lane >> 4;

    f32x4 acc[4][2];
    #pragma unroll
    for (int mt = 0; mt < 4; ++mt)
        #pragma unroll
        for (int nt = 0; nt < 2; ++nt)
            acc[mt][nt] = f32x4{0.f, 0.f, 0.f, 0.f};

    #pragma unroll
    for (int s = 0; s < 4; ++s) {
        const int kk = s * 4 + lkb;
        short8 af[4], bfr[2];
        #pragma unroll
        for (int mt = 0; mt < 4; ++mt)
            af[mt] = xs[kk * BM + ((wm + mt * 16 + lrow) ^ kk)];
        #pragma unroll
        for (int nt = 0; nt < 2; ++nt)
            bfr[nt] = ws[kk * BN + wn + nt * 16 + lrow];
        #pragma unroll
        for (int mt = 0; mt < 4; ++mt)
            #pragma unroll
            for (int nt = 0; nt < 2; ++nt)
                acc[mt][nt] = __builtin_amdgcn_mfma_f32_16x16x32_bf16(
                    af[mt], bfr[nt], acc[mt][nt], 0, 0, 0);
    }

    // C/D layout: col = lane&15, row = (lane>>4)*4 + reg
    const int crow0 = (lane >> 4) * 4;
    #pragma unroll
    for (int mt = 0; mt < 4; ++mt) {
        #pragma unroll
        for (int r2 = 0; r2 < 4; ++r2) {
            const int m = node0 + wm + mt * 16 + crow0 + r2;
            if (m < nNodes) {
                #pragma unroll
                for (int nt = 0; nt < 2; ++nt)
                    outp[(size_t)m * 128 + ncol0 + wn + nt * 16 + lrow] =
                        f2bf(acc[mt][nt][r2]);
            }
        }
    }
}

// Phase 2: out[e] = sigmoid( relu(A[row] + B[col] + b1) . W2 + b2 )
// 16 lanes per edge; lane sub owns hidden elems [sub*8, sub*8+8).
__global__ __launch_bounds__(256) void ep_edges(
    const int* __restrict__ ei,
    const unsigned short* __restrict__ A, const unsigned short* __restrict__ B,
    const float* __restrict__ b1, const float* __restrict__ W2,
    const float* __restrict__ b2, float* __restrict__ out, int E)
{
    const int sub = threadIdx.x & 15;
    float b1f[8], w2f[8];
    #pragma unroll
    for (int j = 0; j < 8; ++j) {
        b1f[j] = b1[sub * 8 + j];
        w2f[j] = W2[sub * 8 + j];
    }
    const float b2v = b2[0];

    const size_t stride = ((size_t)gridDim.x * blockDim.x) >> 4;
    for (size_t e = ((size_t)blockIdx.x * blockDim.x + threadIdx.x) >> 4;
         e < (size_t)E; e += stride) {
        const size_t r = (size_t)(unsigned)ei[e];
        const size_t c = (size_t)(unsigned)ei[E + e];

        const short8 a8 = *reinterpret_cast<const short8*>(A + r * 128 + sub * 8);
        const short8 v8 = *reinterpret_cast<const short8*>(B + c * 128 + sub * 8);

        float p = 0.f;
        #pragma unroll
        for (int j = 0; j < 8; ++j) {
            const float h = fmaxf(bf2f((unsigned short)a8[j]) +
                                  bf2f((unsigned short)v8[j]) + b1f[j], 0.f);
            p = fmaf(h, w2f[j], p);
        }

        p += __shfl_xor(p, 1);
        p += __shfl_xor(p, 2);
        p += __shfl_xor(p, 4);
        p += __shfl_xor(p, 8);

        if (sub == 0) out[e] = 1.f / (1.f + expf(-(p + b2v)));
    }
}

extern "C" void kernel_launch(void* const* d_in, const int* in_sizes, int n_in,
                              void* d_out, int out_size, void* d_ws, size_t ws_size,
                              hipStream_t stream) {
    const float* x  = (const float*)d_in[0];
    const int*   ei = (const int*)  d_in[1];
    const float* W1 = (const float*)d_in[2];
    const float* b1 = (const float*)d_in[3];
    const float* W2 = (const float*)d_in[4];
    const float* b2 = (const float*)d_in[5];
    float* out = (float*)d_out;

    const int nNodes = in_sizes[0] / 128;     // 50000
    const int E      = in_sizes[1] / 2;       // 600000

    unsigned short* A   = (unsigned short*)d_ws;          // [nNodes][128] bf16
    unsigned short* B   = A + (size_t)nNodes * 128;       // [nNodes][128] bf16
    unsigned short* W1s = B + (size_t)nNodes * 128;       // 2*16*128*8 bf16 = 64 KiB

    ep_prepw<<<16, 256, 0, stream>>>(W1, W1s);

    const int mblocks = (nNodes + BM - 1) / BM;
    const int nwg = mblocks * 4;
    ep_gemm<<<nwg, 256, 0, stream>>>(x, W1s, A, B, nNodes, nwg);

    const int needed = (int)(((size_t)E * 16 + 255) / 256);
    const int edge_blocks = needed < 4096 ? needed : 4096;
    ep_edges<<<edge_blocks, 256, 0, stream>>>(ei, A, B, b1, W2, b2, out, E);
}

// Round 4
// 55.954 us; speedup vs baseline: 2.9767x; 1.2202x over previous
//
#include <hip/hip_runtime.h>
#include <hip/hip_bf16.h>
#include <math.h>

typedef __attribute__((ext_vector_type(8))) short short8;
typedef __attribute__((ext_vector_type(4))) float f32x4;

static __device__ __forceinline__ unsigned short f2bf(float f) {
    __hip_bfloat16 h = __float2bfloat16(f);
    return *reinterpret_cast<unsigned short*>(&h);
}

// Prep: W1s[h][kb][col][j] = bf16(W1[h*128 + kb*8 + j][col]) — the exact ws
// LDS layout ep_gemm stages, so gemm's W staging is a linear b128 copy.
__global__ __launch_bounds__(256) void ep_prepw(
    const float* __restrict__ W1, unsigned short* __restrict__ W1s)
{
    const int gid = blockIdx.x * 256 + threadIdx.x;   // 4096 = 2*16*128
    const int h   = gid >> 11;
    const int kb  = (gid >> 7) & 15;
    const int col = gid & 127;
    short8 v;
    #pragma unroll
    for (int j = 0; j < 8; ++j)
        v[j] = (short)f2bf(W1[(size_t)(h * 128 + kb * 8 + j) * 128 + col]);
    reinterpret_cast<short8*>(W1s)[gid] = v;
}

// Phase 1: A = x@W1top (+b1 folded), B = x@W1bot, quantized to int8 with a
// per-row scale (rowmax/127). Block = 128 nodes x ALL 128 cols (so the
// row-max reduction stays inside one wave); h = which half of W1.
// 4 waves, per-wave tile 32 rows x 128 cols (acc[2][8] f32x4 = 64 VGPR).
#define BM 128

__global__ __launch_bounds__(256) void ep_gemm(
    const float* __restrict__ x, const unsigned short* __restrict__ W1s,
    const float* __restrict__ b1,
    signed char* __restrict__ Aq, signed char* __restrict__ Bq,
    float* __restrict__ Ascale, float* __restrict__ Bscale,
    int nNodes, int nwg)
{
    __shared__ short8 xs[16 * BM];   // 32 KiB: [kb][row^kb]
    __shared__ short8 ws[16 * 128];  // 32 KiB: [kb][col]

    const int tid = threadIdx.x;

    // bijective XCD grouping: A/B siblings of an Mblk share an XCD (x reuse)
    const int orig = blockIdx.x;
    const int q = nwg >> 3, r = nwg & 7;
    const int xcd = orig & 7, within = orig >> 3;
    const int base = (xcd < r) ? xcd * (q + 1) : r * (q + 1) + (xcd - r) * q;
    const int gi = base + within;

    const int Mblk  = gi >> 1;
    const int h     = gi & 1;
    const int node0 = Mblk * BM;
    signed char* __restrict__ outq = h ? Bq : Aq;
    float* __restrict__ outs = h ? Bscale : Ascale;

    // stage x tile (swizzled slot kb*128 + (row^kb): conflict-free writes)
    #pragma unroll
    for (int i = 0; i < 8; ++i) {
        const int c = tid + i * 256;
        const int row = c >> 4, kb = c & 15;
        const int node = node0 + row;
        short8 v;
        if (node < nNodes) {
            const float4* src = reinterpret_cast<const float4*>(x + (size_t)node * 128 + kb * 8);
            const float4 p0 = src[0], p1 = src[1];
            v[0] = (short)f2bf(p0.x); v[1] = (short)f2bf(p0.y);
            v[2] = (short)f2bf(p0.z); v[3] = (short)f2bf(p0.w);
            v[4] = (short)f2bf(p1.x); v[5] = (short)f2bf(p1.y);
            v[6] = (short)f2bf(p1.z); v[7] = (short)f2bf(p1.w);
        } else {
            v = short8{0, 0, 0, 0, 0, 0, 0, 0};
        }
        xs[kb * BM + (row ^ kb)] = v;
    }
    // stage W half: linear 32 KiB copy from pre-transposed W1s (L2-resident)
    #pragma unroll
    for (int i = 0; i < 8; ++i) {
        const int c = tid + i * 256;
        ws[c] = reinterpret_cast<const short8*>(W1s)[h * 2048 + c];
    }
    __syncthreads();

    const int w = tid >> 6, lane = tid & 63;
    const int wm = w * 32;
    const int lrow = lane & 15, lkb = lane >> 4;

    f32x4 acc[2][8];
    #pragma unroll
    for (int mt = 0; mt < 2; ++mt)
        #pragma unroll
        for (int nt = 0; nt < 8; ++nt)
            acc[mt][nt] = f32x4{0.f, 0.f, 0.f, 0.f};

    #pragma unroll
    for (int s = 0; s < 4; ++s) {
        const int kk = s * 4 + lkb;
        short8 af[2], bfr[8];
        #pragma unroll
        for (int mt = 0; mt < 2; ++mt)
            af[mt] = xs[kk * BM + ((wm + mt * 16 + lrow) ^ kk)];
        #pragma unroll
        for (int nt = 0; nt < 8; ++nt)
            bfr[nt] = ws[kk * 128 + nt * 16 + lrow];
        #pragma unroll
        for (int mt = 0; mt < 2; ++mt)
            #pragma unroll
            for (int nt = 0; nt < 8; ++nt)
                acc[mt][nt] = __builtin_amdgcn_mfma_f32_16x16x32_bf16(
                    af[mt], bfr[nt], acc[mt][nt], 0, 0, 0);
    }

    // b1 columns this lane owns (col = nt*16 + lrow); fold into A only
    float b1v[8];
    #pragma unroll
    for (int nt = 0; nt < 8; ++nt)
        b1v[nt] = (h == 0) ? b1[nt * 16 + lrow] : 0.f;

    // C/D layout: col = lane&15, row = (lane>>4)*4 + reg.
    // Row-max over 128 cols = per-lane max over nt, then shfl_xor over the
    // 16 lanes sharing lane>>4 (xor bits 1/2/4/8 stay within the group).
    const int crow0 = (lane >> 4) * 4;
    #pragma unroll
    for (int mt = 0; mt < 2; ++mt) {
        #pragma unroll
        for (int r2 = 0; r2 < 4; ++r2) {
            float v[8];
            float m = 0.f;
            #pragma unroll
            for (int nt = 0; nt < 8; ++nt) {
                v[nt] = acc[mt][nt][r2] + b1v[nt];
                m = fmaxf(m, fabsf(v[nt]));
            }
            m = fmaxf(m, __shfl_xor(m, 1));
            m = fmaxf(m, __shfl_xor(m, 2));
            m = fmaxf(m, __shfl_xor(m, 4));
            m = fmaxf(m, __shfl_xor(m, 8));
            const float inv = 127.0f / fmaxf(m, 1e-30f);
            const int row = node0 + wm + mt * 16 + crow0 + r2;
            if (row < nNodes) {
                #pragma unroll
                for (int nt = 0; nt < 8; ++nt) {
                    const int qi = (int)rintf(v[nt] * inv);
                    outq[(size_t)row * 128 + nt * 16 + lrow] = (signed char)qi;
                }
                if (lrow == 0) outs[row] = m * (1.0f / 127.0f);
            }
        }
    }
}

// Phase 2: out[e] = sigmoid( sum_j relu(Aq[r][j]*sa + Bq[c][j]*sb) * W2[j] + b2 )
// (b1 already folded into A). 16 lanes per edge; lane sub owns 8 int8 elems
// = one 8B load per endpoint (row = 128 B, fully coalesced per group).
__global__ __launch_bounds__(256) void ep_edges(
    const int* __restrict__ ei,
    const signed char* __restrict__ Aq, const signed char* __restrict__ Bq,
    const float* __restrict__ Ascale, const float* __restrict__ Bscale,
    const float* __restrict__ W2, const float* __restrict__ b2,
    float* __restrict__ out, int E)
{
    const int sub = threadIdx.x & 15;
    float w2f[8];
    #pragma unroll
    for (int j = 0; j < 8; ++j) w2f[j] = W2[sub * 8 + j];
    const float b2v = b2[0];

    const size_t stride = ((size_t)gridDim.x * blockDim.x) >> 4;
    for (size_t e = ((size_t)blockIdx.x * blockDim.x + threadIdx.x) >> 4;
         e < (size_t)E; e += stride) {
        const size_t r = (size_t)(unsigned)ei[e];
        const size_t c = (size_t)(unsigned)ei[E + e];

        const uint2 qa = *reinterpret_cast<const uint2*>(Aq + r * 128 + sub * 8);
        const uint2 qb = *reinterpret_cast<const uint2*>(Bq + c * 128 + sub * 8);
        const float sa = Ascale[r];
        const float sb = Bscale[c];

        float p = 0.f;
        #pragma unroll
        for (int j = 0; j < 8; ++j) {
            const unsigned ua = (j < 4) ? qa.x : qa.y;
            const unsigned ub = (j < 4) ? qb.x : qb.y;
            const int ia = (int)(signed char)(ua >> (8 * (j & 3)));
            const int ib = (int)(signed char)(ub >> (8 * (j & 3)));
            const float hv = fmaxf(fmaf((float)ia, sa, (float)ib * sb), 0.f);
            p = fmaf(hv, w2f[j], p);
        }

        p += __shfl_xor(p, 1);
        p += __shfl_xor(p, 2);
        p += __shfl_xor(p, 4);
        p += __shfl_xor(p, 8);

        if (sub == 0) out[e] = 1.f / (1.f + expf(-(p + b2v)));
    }
}

extern "C" void kernel_launch(void* const* d_in, const int* in_sizes, int n_in,
                              void* d_out, int out_size, void* d_ws, size_t ws_size,
                              hipStream_t stream) {
    const float* x  = (const float*)d_in[0];
    const int*   ei = (const int*)  d_in[1];
    const float* W1 = (const float*)d_in[2];
    const float* b1 = (const float*)d_in[3];
    const float* W2 = (const float*)d_in[4];
    const float* b2 = (const float*)d_in[5];
    float* out = (float*)d_out;

    const int nNodes = in_sizes[0] / 128;     // 50000
    const int E      = in_sizes[1] / 2;       // 600000

    // workspace layout (all 64B-aligned)
    unsigned short* W1s = (unsigned short*)d_ws;                 // 64 KiB
    signed char* Aq     = (signed char*)(W1s + 2 * 2048 * 8);    // nNodes*128
    signed char* Bq     = Aq + (size_t)nNodes * 128;             // nNodes*128
    float* Ascale       = (float*)(Bq + (size_t)nNodes * 128);   // nNodes f32
    float* Bscale       = Ascale + nNodes;                       // nNodes f32

    ep_prepw<<<16, 256, 0, stream>>>(W1, W1s);

    const int mblocks = (nNodes + BM - 1) / BM;
    const int nwg = mblocks * 2;
    ep_gemm<<<nwg, 256, 0, stream>>>(x, W1s, b1, Aq, Bq, Ascale, Bscale, nNodes, nwg);

    const int needed = (int)(((size_t)E * 16 + 255) / 256);
    const int edge_blocks = needed < 4096 ? needed : 4096;
    ep_edges<<<edge_blocks, 256, 0, stream>>>(ei, Aq, Bq, Ascale, Bscale, W2, b2, out, E);
}